// Round 15
// baseline (810.793 us; speedup 1.0000x reference)
//
#include <hip/hip_runtime.h>

#define CDIV(a,b) (((a)+(b)-1)/(b))
#define BUK_SHIFT 10
#define EPB 4096   // edges per bucketize block

typedef float f32x4 __attribute__((ext_vector_type(4)));
typedef short short8 __attribute__((ext_vector_type(8)));
typedef _Float16 h16x8 __attribute__((ext_vector_type(8)));

// ---------------- bf16 helpers (RNE) ----------------

__device__ inline unsigned short rne_bf16(float f) {
    unsigned int u = __builtin_bit_cast(unsigned int, f);
    u += 0x7FFFu + ((u >> 16) & 1u);
    return (unsigned short)(u >> 16);
}

struct BF16Pair { short hi, lo; };

__device__ inline BF16Pair split_bf16(float f) {
    unsigned short h = rne_bf16(f);
    float fh = __builtin_bit_cast(float, (unsigned int)h << 16);
    BF16Pair p;
    p.hi = (short)h;
    p.lo = (short)rne_bf16(f - fh);
    return p;
}

// ---------------- bucketed edge sort ----------------

__global__ __launch_bounds__(256) void bkt_hist_kernel(const int* __restrict__ dst,
                                                       int* __restrict__ hcnt,
                                                       int E, int nbuk, int nblk) {
    __shared__ int lh[128];
    int t = threadIdx.x;
    for (int i = t; i < nbuk; i += 256) lh[i] = 0;
    __syncthreads();
    int base = blockIdx.x * EPB;
    int end = min(base + EPB, E);
    for (int e = base + t; e < end; e += 256)
        atomicAdd(&lh[dst[e] >> BUK_SHIFT], 1);
    __syncthreads();
    for (int i = t; i < nbuk; i += 256) hcnt[i * nblk + blockIdx.x] = lh[i];
}

__global__ __launch_bounds__(1024) void scan_flat_kernel(int* a, int n) {
    __shared__ int s[1024];
    int t = threadIdx.x;
    int per = (n + 1023) / 1024;
    int start = t * per, end = min(start + per, n);
    int sum = 0;
    for (int i = start; i < end; ++i) sum += a[i];
    s[t] = sum;
    __syncthreads();
    for (int off = 1; off < 1024; off <<= 1) {
        int x = (t >= off) ? s[t - off] : 0;
        __syncthreads();
        s[t] += x;
        __syncthreads();
    }
    int run = s[t] - sum;
    for (int i = start; i < end; ++i) { int v = a[i]; a[i] = run; run += v; }
}

__global__ __launch_bounds__(256) void bkt_scatter_kernel(const int* __restrict__ src,
                                                          const int* __restrict__ dst,
                                                          const int* __restrict__ obk,
                                                          unsigned long long* __restrict__ ebuf,
                                                          int E, int nbuk, int nblk) {
    __shared__ int cur[128];
    int t = threadIdx.x;
    for (int i = t; i < nbuk; i += 256) cur[i] = obk[i * nblk + blockIdx.x];
    __syncthreads();
    int base = blockIdx.x * EPB;
    int end = min(base + EPB, E);
    for (int e = base + t; e < end; e += 256) {
        int d = dst[e], s = src[e];
        int b = d >> BUK_SHIFT;
        int pos = atomicAdd(&cur[b], 1);
        ebuf[pos] = ((unsigned long long)(unsigned)d << 32) | (unsigned)s;
    }
}

// ---------------- fused per-bucket CSR build (hist+scan+rp+dinv+fill) ----------------

__global__ __launch_bounds__(1024) void bucket_csr_kernel(const unsigned long long* __restrict__ ebuf,
                                                          const int* __restrict__ hcnt,
                                                          int* __restrict__ rp,
                                                          float* __restrict__ dinv,
                                                          int* __restrict__ col,
                                                          int E, int N, int nbuk, int nblk) {
    __shared__ int lh[1024];
    __shared__ int lsc[1024];
    const int b = blockIdx.x;
    const int t = threadIdx.x;
    lh[t] = 0;
    __syncthreads();
    const int st = hcnt[b * nblk];
    const int en = (b + 1 < nbuk) ? hcnt[(b + 1) * nblk] : E;
    for (int e = st + t; e < en; e += 1024)
        atomicAdd(&lh[((int)(unsigned)(ebuf[e] >> 32)) & 1023], 1);
    __syncthreads();
    const int deg = lh[t];
    lsc[t] = deg;
    __syncthreads();
    for (int off = 1; off < 1024; off <<= 1) {
        int x = (t >= off) ? lsc[t - off] : 0;
        __syncthreads();
        lsc[t] += x;
        __syncthreads();
    }
    const int excl = lsc[t] - deg;
    const int node = (b << BUK_SHIFT) + t;
    if (node < N) {
        rp[node] = st + excl;
        dinv[node] = rsqrtf((float)deg + 1.0f);
    }
    if (b == 0 && t == 0) rp[N] = E;
    __syncthreads();
    lh[t] = st + excl;
    __syncthreads();
    for (int e = st + t; e < en; e += 1024) {
        unsigned long long r = ebuf[e];
        int d = (int)(unsigned)(r >> 32);
        int pos = atomicAdd(&lh[d & 1023], 1);
        col[pos] = (int)(unsigned)(r & 0xFFFFFFFFull);
    }
}

// ---------------- W prep: fp32 [K][F] -> split-bf16 in MFMA B-fragment order ----

template<int K, int F>
__global__ void wprep_kernel(const float* __restrict__ W, short* __restrict__ whi,
                             short* __restrict__ wlo) {
    constexpr int CB = F / 16;
    int idx = blockIdx.x * 256 + threadIdx.x;
    if (idx >= K * F) return;
    int e = idx & 7;
    int lane = (idx >> 3) & 63;
    int fc = idx >> 9;               // kb*CB + cb
    int kb = fc / CB, cb = fc % CB;
    int k = kb * 32 + (lane >> 4) * 8 + e;
    int colv = cb * 16 + (lane & 15);
    BF16Pair p = split_bf16(W[k * F + colv]);
    whi[idx] = p.hi;
    wlo[idx] = p.lo;
}

// ---------------- MFMA GEMM: H[N,F] = fp16( dinv[r] * (A[N,K] @ W[K,F]) ) --------
// MT=1, B double-buffered in LDS, raw s_barrier + counted waits.

template<int K, int F, typename AT>
__global__ __launch_bounds__(256) void mfma_gemm(const AT* __restrict__ A,
                                                 const short* __restrict__ Whi,
                                                 const short* __restrict__ Wlo,
                                                 const float* __restrict__ dinv,
                                                 _Float16* __restrict__ H, int N) {
    constexpr int CB = F / 16;
    constexpr int KB = K / 32;
    constexpr int HCH = CB * 64;
    constexpr int CHUNKS = HCH * 2;
    constexpr int CPT = (CHUNKS + 255) / 256;

    __shared__ __align__(16) short Bs[2][CB * 1024];

    const int tid = threadIdx.x;
    const int wid = tid >> 6, lane = tid & 63;
    const int rowf = lane & 15;
    const int kgrp = lane >> 4;
    const long long row0 = (long long)blockIdx.x * 64 + wid * 16;

    f32x4 acc[CB] = {};
    short8 breg[CPT];
    float fvaC[8], fvaN[8];

    auto stage_issue = [&](int kb) {
#pragma unroll
        for (int i = 0; i < CPT; ++i) {
            int c = tid + i * 256;
            if (CHUNKS < 256 && c >= CHUNKS) continue;
            const short* p = (c < HCH) ? (Whi + (size_t)kb * (CB * 512) + (size_t)c * 8)
                                       : (Wlo + (size_t)kb * (CB * 512) + (size_t)(c - HCH) * 8);
            breg[i] = *(const short8*)p;
        }
    };
    auto stage_write = [&](int b) {
#pragma unroll
        for (int i = 0; i < CPT; ++i) {
            int c = tid + i * 256;
            if (CHUNKS < 256 && c >= CHUNKS) continue;
            *(short8*)&Bs[b][(size_t)c * 8] = breg[i];
        }
    };
    auto a_load = [&](float (&dst)[8], int kb) {
        long long r = row0 + rowf;
        if (r < N) {
            const AT* ap = A + (size_t)r * K + kb * 32 + kgrp * 8;
            if constexpr (sizeof(AT) == 4) {
                float4 f0 = ((const float4*)ap)[0];
                float4 f1 = ((const float4*)ap)[1];
                dst[0]=f0.x; dst[1]=f0.y; dst[2]=f0.z; dst[3]=f0.w;
                dst[4]=f1.x; dst[5]=f1.y; dst[6]=f1.z; dst[7]=f1.w;
            } else {
                h16x8 hv = *(const h16x8*)ap;
#pragma unroll
                for (int j = 0; j < 8; ++j) dst[j] = (float)hv[j];
            }
        } else {
#pragma unroll
            for (int j = 0; j < 8; ++j) dst[j] = 0.f;
        }
    };

    stage_issue(0);
    a_load(fvaC, 0);

    for (int kb = 0; kb < KB; ++kb) {
        const int b = kb & 1;
        stage_write(b);
        if (kb + 1 < KB) stage_issue(kb + 1);
        asm volatile("s_waitcnt lgkmcnt(0)" ::: "memory");
        __builtin_amdgcn_s_barrier();
        __builtin_amdgcn_sched_barrier(0);
        if (kb + 1 < KB) a_load(fvaN, kb + 1);

        short8 ahi, alo;
#pragma unroll
        for (int j = 0; j < 8; ++j) {
            BF16Pair p = split_bf16(fvaC[j]);
            ahi[j] = p.hi;
            alo[j] = p.lo;
        }
#pragma unroll
        for (int cb = 0; cb < CB; ++cb) {
            short8 bhi = *(const short8*)&Bs[b][((size_t)cb * 64 + lane) * 8];
            short8 blo = *(const short8*)&Bs[b][CB * 512 + ((size_t)cb * 64 + lane) * 8];
            acc[cb] = __builtin_amdgcn_mfma_f32_16x16x32_bf16(ahi, bhi, acc[cb], 0, 0, 0);
            acc[cb] = __builtin_amdgcn_mfma_f32_16x16x32_bf16(alo, bhi, acc[cb], 0, 0, 0);
            acc[cb] = __builtin_amdgcn_mfma_f32_16x16x32_bf16(ahi, blo, acc[cb], 0, 0, 0);
        }
#pragma unroll
        for (int j = 0; j < 8; ++j) fvaC[j] = fvaN[j];
    }

    const int rsub = (lane >> 4) * 4;
    long long rbase = row0 + rsub;
    float dv[4];
#pragma unroll
    for (int j = 0; j < 4; ++j) dv[j] = (rbase + j < N) ? dinv[rbase + j] : 0.f;
#pragma unroll
    for (int cb = 0; cb < CB; ++cb) {
        int colv = cb * 16 + rowf;
#pragma unroll
        for (int j = 0; j < 4; ++j) {
            long long r = rbase + j;
            if (r < N) H[(size_t)r * F + colv] = (_Float16)(acc[cb][j] * dv[j]);
        }
    }
}

// ---------------- XCD-sliced CSR aggregation (fp16 gather, fp32 accum) ----------------
// slice = blockIdx.x & (SLICES-1): workgroups round-robin across the 8 XCDs, so
// XCD x only touches feature cols [16*(x%SLICES), +16) -> per-XCD gather
// footprint = N*32B = 3.2MB < 4MB L2. 2 lanes/node (8 fp16 = 16B each).

template<int F, bool RELU, typename OutT>
__global__ __launch_bounds__(256) void agg_slice_kernel(const _Float16* __restrict__ hs,
                                                        const int* __restrict__ rp,
                                                        const int* __restrict__ col,
                                                        const float* __restrict__ dinv,
                                                        const float* __restrict__ bias,
                                                        OutT* __restrict__ out, int N) {
    constexpr int SLICES = F / 16;
    const int slice = blockIdx.x & (SLICES - 1);
    const int node = (int)(blockIdx.x / SLICES) * 128 + (threadIdx.x >> 1);
    if (node >= N) return;

    const int f0 = slice * 16 + (threadIdx.x & 1) * 8;
    const _Float16* hbase = hs + f0;

    float acc[8];
    {
        h16x8 sv = *(const h16x8*)(hbase + (size_t)node * F);
#pragma unroll
        for (int v = 0; v < 8; ++v) acc[v] = (float)sv[v];
    }

    int e = rp[node];
    const int e1 = rp[node + 1];
    for (; e + 4 <= e1; e += 4) {
        int s0 = col[e], s1 = col[e + 1], s2 = col[e + 2], s3 = col[e + 3];
        h16x8 v0 = *(const h16x8*)(hbase + (size_t)s0 * F);
        h16x8 v1 = *(const h16x8*)(hbase + (size_t)s1 * F);
        h16x8 v2 = *(const h16x8*)(hbase + (size_t)s2 * F);
        h16x8 v3 = *(const h16x8*)(hbase + (size_t)s3 * F);
#pragma unroll
        for (int v = 0; v < 8; ++v)
            acc[v] += ((float)v0[v] + (float)v1[v]) + ((float)v2[v] + (float)v3[v]);
    }
    for (; e < e1; ++e) {
        h16x8 v0 = *(const h16x8*)(hbase + (size_t)col[e] * F);
#pragma unroll
        for (int v = 0; v < 8; ++v) acc[v] += (float)v0[v];
    }

    const float self = dinv[node];
    OutT* op = out + (size_t)node * F + f0;
    const float* bp = bias + f0;
#pragma unroll
    for (int v = 0; v < 8; ++v) {
        float r = fmaf(acc[v], self, bp[v]);
        if (RELU) r = fmaxf(r, 0.f);
        op[v] = (OutT)r;
    }
}

// ---------------- launcher ----------------

extern "C" void kernel_launch(void* const* d_in, const int* in_sizes, int n_in,
                              void* d_out, int out_size, void* d_ws, size_t ws_size,
                              hipStream_t stream) {
    const float* x  = (const float*)d_in[0];
    const int*   ei = (const int*)d_in[1];
    const float* W1 = (const float*)d_in[2];
    const float* b1 = (const float*)d_in[3];
    const float* W2 = (const float*)d_in[4];
    const float* b2 = (const float*)d_in[5];
    const float* W3 = (const float*)d_in[6];
    const float* b3 = (const float*)d_in[7];
    const float* W4 = (const float*)d_in[8];
    const float* b4 = (const float*)d_in[9];

    const int N = in_sizes[0] / 256;
    const int E = in_sizes[1] / 2;
    const int* src = ei;
    const int* dst = ei + E;

    const int nbuk = ((N - 1) >> BUK_SHIFT) + 1;
    const int nblk = CDIV(E, EPB);

    char* base = (char*)d_ws;
    size_t o = 0;
    auto alloc = [&](size_t bytes) { char* p = base + o; o += (bytes + 255) & ~(size_t)255; return p; };
    int*   rp   = (int*)  alloc(sizeof(int) * (N + 1));
    float* dinv = (float*)alloc(sizeof(float) * N);
    int*   col  = (int*)  alloc(sizeof(int) * E);
    int*   hcnt = (int*)  alloc(sizeof(int) * (size_t)nbuk * nblk);
    unsigned long long* ebuf = (unsigned long long*)alloc(sizeof(unsigned long long) * E);
    short* w1h  = (short*)alloc(sizeof(short) * 256 * 128);
    short* w1l  = (short*)alloc(sizeof(short) * 256 * 128);
    short* w2h  = (short*)alloc(sizeof(short) * 128 * 128);
    short* w2l  = (short*)alloc(sizeof(short) * 128 * 128);
    short* w3h  = (short*)alloc(sizeof(short) * 128 * 64);
    short* w3l  = (short*)alloc(sizeof(short) * 128 * 64);
    short* w4h  = (short*)alloc(sizeof(short) * 64 * 32);
    short* w4l  = (short*)alloc(sizeof(short) * 64 * 32);
    _Float16* hsA = (_Float16*)alloc(sizeof(_Float16) * (size_t)N * 128);  // ping
    _Float16* hsB = (_Float16*)alloc(sizeof(_Float16) * (size_t)N * 128);  // pong
    float* out  = (float*)d_out;

    // --- weight prep (split-bf16, fragment-swizzled) ---
    wprep_kernel<256, 128><<<CDIV(256 * 128, 256), 256, 0, stream>>>(W1, w1h, w1l);
    wprep_kernel<128, 128><<<CDIV(128 * 128, 256), 256, 0, stream>>>(W2, w2h, w2l);
    wprep_kernel<128, 64><<<CDIV(128 * 64, 256), 256, 0, stream>>>(W3, w3h, w3l);
    wprep_kernel<64, 32><<<CDIV(64 * 32, 256), 256, 0, stream>>>(W4, w4h, w4l);

    // --- bucketed edge sort + fused CSR build ---
    bkt_hist_kernel<<<nblk, 256, 0, stream>>>(dst, hcnt, E, nbuk, nblk);
    scan_flat_kernel<<<1, 1024, 0, stream>>>(hcnt, nbuk * nblk);
    bkt_scatter_kernel<<<nblk, 256, 0, stream>>>(src, dst, hcnt, ebuf, E, nbuk, nblk);
    bucket_csr_kernel<<<nbuk, 1024, 0, stream>>>(ebuf, hcnt, rp, dinv, col, E, N, nbuk, nblk);

    const int GG = CDIV(N, 64);
    const int AG = CDIV(N, 128);   // node-groups per agg slice launch

    // --- layer 1 ---
    mfma_gemm<256, 128, float><<<GG, 256, 0, stream>>>(x, w1h, w1l, dinv, hsA, N);
    agg_slice_kernel<128, true, _Float16><<<AG * 8, 256, 0, stream>>>(hsA, rp, col, dinv, b1, hsB, N);

    // --- layer 2 ---
    mfma_gemm<128, 128, _Float16><<<GG, 256, 0, stream>>>(hsB, w2h, w2l, dinv, hsA, N);
    agg_slice_kernel<128, true, _Float16><<<AG * 8, 256, 0, stream>>>(hsA, rp, col, dinv, b2, hsB, N);

    // --- layer 3 ---
    mfma_gemm<128, 64, _Float16><<<GG, 256, 0, stream>>>(hsB, w3h, w3l, dinv, hsA, N);
    agg_slice_kernel<64, true, _Float16><<<AG * 4, 256, 0, stream>>>(hsA, rp, col, dinv, b3, hsB, N);

    // --- layer 4 ---
    mfma_gemm<64, 32, _Float16><<<GG, 256, 0, stream>>>(hsB, w4h, w4l, dinv, hsA, N);
    agg_slice_kernel<32, false, float><<<AG * 2, 256, 0, stream>>>(hsA, rp, col, dinv, b4, out, N);
}

// Round 16
// 363.924 us; speedup vs baseline: 2.2279x; 2.2279x over previous
//
#include <hip/hip_runtime.h>

#define CDIV(a,b) (((a)+(b)-1)/(b))
#define BUK_SHIFT 10
#define EPB 4096   // edges per bucketize block

typedef float f32x4 __attribute__((ext_vector_type(4)));
typedef short short8 __attribute__((ext_vector_type(8)));
typedef _Float16 h16x8 __attribute__((ext_vector_type(8)));

// ---------------- bf16 helpers (RNE) ----------------

__device__ inline unsigned short rne_bf16(float f) {
    unsigned int u = __builtin_bit_cast(unsigned int, f);
    u += 0x7FFFu + ((u >> 16) & 1u);
    return (unsigned short)(u >> 16);
}

struct BF16Pair { short hi, lo; };

__device__ inline BF16Pair split_bf16(float f) {
    unsigned short h = rne_bf16(f);
    float fh = __builtin_bit_cast(float, (unsigned int)h << 16);
    BF16Pair p;
    p.hi = (short)h;
    p.lo = (short)rne_bf16(f - fh);
    return p;
}

// ---------------- bucketed edge sort (u32 records: (dst&1023)<<22 | src) ----------------

__global__ __launch_bounds__(256) void bkt_hist_kernel(const int* __restrict__ dst,
                                                       int* __restrict__ hcnt,
                                                       int E, int nbuk, int nblk) {
    __shared__ int lh[128];
    int t = threadIdx.x;
    for (int i = t; i < nbuk; i += 256) lh[i] = 0;
    __syncthreads();
    int base = blockIdx.x * EPB;
    int end = min(base + EPB, E);
    for (int e = base + t; e < end; e += 256)
        atomicAdd(&lh[dst[e] >> BUK_SHIFT], 1);
    __syncthreads();
    for (int i = t; i < nbuk; i += 256) hcnt[i * nblk + blockIdx.x] = lh[i];
}

__global__ __launch_bounds__(1024) void scan_flat_kernel(int* a, int n) {
    __shared__ int s[1024];
    int t = threadIdx.x;
    int per = (n + 1023) / 1024;
    int start = t * per, end = min(start + per, n);
    int sum = 0;
    for (int i = start; i < end; ++i) sum += a[i];
    s[t] = sum;
    __syncthreads();
    for (int off = 1; off < 1024; off <<= 1) {
        int x = (t >= off) ? s[t - off] : 0;
        __syncthreads();
        s[t] += x;
        __syncthreads();
    }
    int run = s[t] - sum;
    for (int i = start; i < end; ++i) { int v = a[i]; a[i] = run; run += v; }
}

__global__ __launch_bounds__(256) void bkt_scatter_kernel(const int* __restrict__ src,
                                                          const int* __restrict__ dst,
                                                          const int* __restrict__ obk,
                                                          unsigned int* __restrict__ ebuf,
                                                          int E, int nbuk, int nblk) {
    __shared__ int cur[128];
    int t = threadIdx.x;
    for (int i = t; i < nbuk; i += 256) cur[i] = obk[i * nblk + blockIdx.x];
    __syncthreads();
    int base = blockIdx.x * EPB;
    int end = min(base + EPB, E);
    for (int e = base + t; e < end; e += 256) {
        int d = dst[e], s = src[e];
        int b = d >> BUK_SHIFT;
        int pos = atomicAdd(&cur[b], 1);
        ebuf[pos] = ((unsigned)(d & 1023) << 22) | (unsigned)s;   // src < 2^22
    }
}

// ---------------- fused per-bucket CSR build (hist+scan+rp+dinv+fill) ----------------

__global__ __launch_bounds__(1024) void bucket_csr_kernel(const unsigned int* __restrict__ ebuf,
                                                          const int* __restrict__ hcnt,
                                                          int* __restrict__ rp,
                                                          float* __restrict__ dinv,
                                                          int* __restrict__ col,
                                                          int E, int N, int nbuk, int nblk) {
    __shared__ int lh[1024];
    __shared__ int lsc[1024];
    const int b = blockIdx.x;
    const int t = threadIdx.x;
    lh[t] = 0;
    __syncthreads();
    const int st = hcnt[b * nblk];
    const int en = (b + 1 < nbuk) ? hcnt[(b + 1) * nblk] : E;
    for (int e = st + t; e < en; e += 1024)
        atomicAdd(&lh[ebuf[e] >> 22], 1);
    __syncthreads();
    const int deg = lh[t];
    lsc[t] = deg;
    __syncthreads();
    for (int off = 1; off < 1024; off <<= 1) {
        int x = (t >= off) ? lsc[t - off] : 0;
        __syncthreads();
        lsc[t] += x;
        __syncthreads();
    }
    const int excl = lsc[t] - deg;
    const int node = (b << BUK_SHIFT) + t;
    if (node < N) {
        rp[node] = st + excl;
        dinv[node] = rsqrtf((float)deg + 1.0f);
    }
    if (b == 0 && t == 0) rp[N] = E;
    __syncthreads();
    lh[t] = st + excl;
    __syncthreads();
    for (int e = st + t; e < en; e += 1024) {
        unsigned int r = ebuf[e];
        int pos = atomicAdd(&lh[r >> 22], 1);
        col[pos] = (int)(r & 0x3FFFFFu);
    }
}

// ---------------- W prep: fp32 [K][F] -> split-bf16 in MFMA B-fragment order ----

template<int K, int F>
__global__ void wprep_kernel(const float* __restrict__ W, short* __restrict__ whi,
                             short* __restrict__ wlo) {
    constexpr int CB = F / 16;
    int idx = blockIdx.x * 256 + threadIdx.x;
    if (idx >= K * F) return;
    int e = idx & 7;
    int lane = (idx >> 3) & 63;
    int fc = idx >> 9;               // kb*CB + cb
    int kb = fc / CB, cb = fc % CB;
    int k = kb * 32 + (lane >> 4) * 8 + e;
    int colv = cb * 16 + (lane & 15);
    BF16Pair p = split_bf16(W[k * F + colv]);
    whi[idx] = p.hi;
    wlo[idx] = p.lo;
}

// ---------------- MFMA GEMM: H[N,F] = fp16( dinv[r] * (A[N,K] @ W[K,F]) ) --------
// MT=1, B double-buffered in LDS, raw s_barrier + counted waits.

template<int K, int F, typename AT>
__global__ __launch_bounds__(256) void mfma_gemm(const AT* __restrict__ A,
                                                 const short* __restrict__ Whi,
                                                 const short* __restrict__ Wlo,
                                                 const float* __restrict__ dinv,
                                                 _Float16* __restrict__ H, int N) {
    constexpr int CB = F / 16;
    constexpr int KB = K / 32;
    constexpr int HCH = CB * 64;
    constexpr int CHUNKS = HCH * 2;
    constexpr int CPT = (CHUNKS + 255) / 256;

    __shared__ __align__(16) short Bs[2][CB * 1024];

    const int tid = threadIdx.x;
    const int wid = tid >> 6, lane = tid & 63;
    const int rowf = lane & 15;
    const int kgrp = lane >> 4;
    const long long row0 = (long long)blockIdx.x * 64 + wid * 16;

    f32x4 acc[CB] = {};
    short8 breg[CPT];
    float fvaC[8], fvaN[8];

    auto stage_issue = [&](int kb) {
#pragma unroll
        for (int i = 0; i < CPT; ++i) {
            int c = tid + i * 256;
            if (CHUNKS < 256 && c >= CHUNKS) continue;
            const short* p = (c < HCH) ? (Whi + (size_t)kb * (CB * 512) + (size_t)c * 8)
                                       : (Wlo + (size_t)kb * (CB * 512) + (size_t)(c - HCH) * 8);
            breg[i] = *(const short8*)p;
        }
    };
    auto stage_write = [&](int b) {
#pragma unroll
        for (int i = 0; i < CPT; ++i) {
            int c = tid + i * 256;
            if (CHUNKS < 256 && c >= CHUNKS) continue;
            *(short8*)&Bs[b][(size_t)c * 8] = breg[i];
        }
    };
    auto a_load = [&](float (&dst)[8], int kb) {
        long long r = row0 + rowf;
        if (r < N) {
            const AT* ap = A + (size_t)r * K + kb * 32 + kgrp * 8;
            if constexpr (sizeof(AT) == 4) {
                float4 f0 = ((const float4*)ap)[0];
                float4 f1 = ((const float4*)ap)[1];
                dst[0]=f0.x; dst[1]=f0.y; dst[2]=f0.z; dst[3]=f0.w;
                dst[4]=f1.x; dst[5]=f1.y; dst[6]=f1.z; dst[7]=f1.w;
            } else {
                h16x8 hv = *(const h16x8*)ap;
#pragma unroll
                for (int j = 0; j < 8; ++j) dst[j] = (float)hv[j];
            }
        } else {
#pragma unroll
            for (int j = 0; j < 8; ++j) dst[j] = 0.f;
        }
    };

    stage_issue(0);
    a_load(fvaC, 0);

    for (int kb = 0; kb < KB; ++kb) {
        const int b = kb & 1;
        stage_write(b);
        if (kb + 1 < KB) stage_issue(kb + 1);
        asm volatile("s_waitcnt lgkmcnt(0)" ::: "memory");
        __builtin_amdgcn_s_barrier();
        __builtin_amdgcn_sched_barrier(0);
        if (kb + 1 < KB) a_load(fvaN, kb + 1);

        short8 ahi, alo;
#pragma unroll
        for (int j = 0; j < 8; ++j) {
            BF16Pair p = split_bf16(fvaC[j]);
            ahi[j] = p.hi;
            alo[j] = p.lo;
        }
#pragma unroll
        for (int cb = 0; cb < CB; ++cb) {
            short8 bhi = *(const short8*)&Bs[b][((size_t)cb * 64 + lane) * 8];
            short8 blo = *(const short8*)&Bs[b][CB * 512 + ((size_t)cb * 64 + lane) * 8];
            acc[cb] = __builtin_amdgcn_mfma_f32_16x16x32_bf16(ahi, bhi, acc[cb], 0, 0, 0);
            acc[cb] = __builtin_amdgcn_mfma_f32_16x16x32_bf16(alo, bhi, acc[cb], 0, 0, 0);
            acc[cb] = __builtin_amdgcn_mfma_f32_16x16x32_bf16(ahi, blo, acc[cb], 0, 0, 0);
        }
#pragma unroll
        for (int j = 0; j < 8; ++j) fvaC[j] = fvaN[j];
    }

    const int rsub = (lane >> 4) * 4;
    long long rbase = row0 + rsub;
    float dv[4];
#pragma unroll
    for (int j = 0; j < 4; ++j) dv[j] = (rbase + j < N) ? dinv[rbase + j] : 0.f;
#pragma unroll
    for (int cb = 0; cb < CB; ++cb) {
        int colv = cb * 16 + rowf;
#pragma unroll
        for (int j = 0; j < 4; ++j) {
            long long r = rbase + j;
            if (r < N) H[(size_t)r * F + colv] = (_Float16)(acc[cb][j] * dv[j]);
        }
    }
}

// ---------------- fused CSR aggregation (fp16 gather, fp32 accum) ----------------

template<int F, bool RELU, typename OutT>
__global__ __launch_bounds__(256) void agg_kernel(const _Float16* __restrict__ hs,
                                                  const int* __restrict__ rp,
                                                  const int* __restrict__ col,
                                                  const float* __restrict__ dinv,
                                                  const float* __restrict__ bias,
                                                  OutT* __restrict__ out, int N) {
    constexpr int LPN = F / 8;            // lanes per node, 16B/lane
    constexpr int NPB = 256 / LPN;
    const int tid = threadIdx.x;
    const int lane = tid % LPN;
    const int node = blockIdx.x * NPB + tid / LPN;
    if (node >= N) return;

    const int f0 = lane * 8;
    const _Float16* hbase = hs + f0;

    float acc[8];
    {
        h16x8 sv = *(const h16x8*)(hbase + (size_t)node * F);
#pragma unroll
        for (int v = 0; v < 8; ++v) acc[v] = (float)sv[v];
    }

    int e = rp[node];
    const int e1 = rp[node + 1];
    for (; e + 4 <= e1; e += 4) {
        int s0 = col[e], s1 = col[e + 1], s2 = col[e + 2], s3 = col[e + 3];
        h16x8 v0 = *(const h16x8*)(hbase + (size_t)s0 * F);
        h16x8 v1 = *(const h16x8*)(hbase + (size_t)s1 * F);
        h16x8 v2 = *(const h16x8*)(hbase + (size_t)s2 * F);
        h16x8 v3 = *(const h16x8*)(hbase + (size_t)s3 * F);
#pragma unroll
        for (int v = 0; v < 8; ++v)
            acc[v] += ((float)v0[v] + (float)v1[v]) + ((float)v2[v] + (float)v3[v]);
    }
    for (; e < e1; ++e) {
        h16x8 v0 = *(const h16x8*)(hbase + (size_t)col[e] * F);
#pragma unroll
        for (int v = 0; v < 8; ++v) acc[v] += (float)v0[v];
    }

    const float self = dinv[node];
    OutT* op = out + (size_t)node * F + f0;
    const float* bp = bias + f0;
#pragma unroll
    for (int v = 0; v < 8; ++v) {
        float r = fmaf(acc[v], self, bp[v]);
        if (RELU) r = fmaxf(r, 0.f);
        op[v] = (OutT)r;
    }
}

// ---------------- launcher ----------------

extern "C" void kernel_launch(void* const* d_in, const int* in_sizes, int n_in,
                              void* d_out, int out_size, void* d_ws, size_t ws_size,
                              hipStream_t stream) {
    const float* x  = (const float*)d_in[0];
    const int*   ei = (const int*)d_in[1];
    const float* W1 = (const float*)d_in[2];
    const float* b1 = (const float*)d_in[3];
    const float* W2 = (const float*)d_in[4];
    const float* b2 = (const float*)d_in[5];
    const float* W3 = (const float*)d_in[6];
    const float* b3 = (const float*)d_in[7];
    const float* W4 = (const float*)d_in[8];
    const float* b4 = (const float*)d_in[9];

    const int N = in_sizes[0] / 256;
    const int E = in_sizes[1] / 2;
    const int* src = ei;
    const int* dst = ei + E;

    const int nbuk = ((N - 1) >> BUK_SHIFT) + 1;
    const int nblk = CDIV(E, EPB);

    char* base = (char*)d_ws;
    size_t o = 0;
    auto alloc = [&](size_t bytes) { char* p = base + o; o += (bytes + 255) & ~(size_t)255; return p; };
    int*   rp   = (int*)  alloc(sizeof(int) * (N + 1));
    float* dinv = (float*)alloc(sizeof(float) * N);
    int*   col  = (int*)  alloc(sizeof(int) * E);
    int*   hcnt = (int*)  alloc(sizeof(int) * (size_t)nbuk * nblk);
    unsigned int* ebuf = (unsigned int*)alloc(sizeof(unsigned int) * E);
    short* w1h  = (short*)alloc(sizeof(short) * 256 * 128);
    short* w1l  = (short*)alloc(sizeof(short) * 256 * 128);
    short* w2h  = (short*)alloc(sizeof(short) * 128 * 128);
    short* w2l  = (short*)alloc(sizeof(short) * 128 * 128);
    short* w3h  = (short*)alloc(sizeof(short) * 128 * 64);
    short* w3l  = (short*)alloc(sizeof(short) * 128 * 64);
    short* w4h  = (short*)alloc(sizeof(short) * 64 * 32);
    short* w4l  = (short*)alloc(sizeof(short) * 64 * 32);
    _Float16* hsA = (_Float16*)alloc(sizeof(_Float16) * (size_t)N * 128);  // ping
    _Float16* hsB = (_Float16*)alloc(sizeof(_Float16) * (size_t)N * 128);  // pong
    float* out  = (float*)d_out;

    // --- weight prep (split-bf16, fragment-swizzled) ---
    wprep_kernel<256, 128><<<CDIV(256 * 128, 256), 256, 0, stream>>>(W1, w1h, w1l);
    wprep_kernel<128, 128><<<CDIV(128 * 128, 256), 256, 0, stream>>>(W2, w2h, w2l);
    wprep_kernel<128, 64><<<CDIV(128 * 64, 256), 256, 0, stream>>>(W3, w3h, w3l);
    wprep_kernel<64, 32><<<CDIV(64 * 32, 256), 256, 0, stream>>>(W4, w4h, w4l);

    // --- bucketed edge sort + fused CSR build ---
    bkt_hist_kernel<<<nblk, 256, 0, stream>>>(dst, hcnt, E, nbuk, nblk);
    scan_flat_kernel<<<1, 1024, 0, stream>>>(hcnt, nbuk * nblk);
    bkt_scatter_kernel<<<nblk, 256, 0, stream>>>(src, dst, hcnt, ebuf, E, nbuk, nblk);
    bucket_csr_kernel<<<nbuk, 1024, 0, stream>>>(ebuf, hcnt, rp, dinv, col, E, N, nbuk, nblk);

    const int GG = CDIV(N, 64);

    // --- layer 1 ---
    mfma_gemm<256, 128, float><<<GG, 256, 0, stream>>>(x, w1h, w1l, dinv, hsA, N);
    agg_kernel<128, true, _Float16><<<CDIV(N, 16), 256, 0, stream>>>(hsA, rp, col, dinv, b1, hsB, N);

    // --- layer 2 ---
    mfma_gemm<128, 128, _Float16><<<GG, 256, 0, stream>>>(hsB, w2h, w2l, dinv, hsA, N);
    agg_kernel<128, true, _Float16><<<CDIV(N, 16), 256, 0, stream>>>(hsA, rp, col, dinv, b2, hsB, N);

    // --- layer 3 ---
    mfma_gemm<128, 64, _Float16><<<GG, 256, 0, stream>>>(hsB, w3h, w3l, dinv, hsA, N);
    agg_kernel<64, true, _Float16><<<CDIV(N, 32), 256, 0, stream>>>(hsA, rp, col, dinv, b3, hsB, N);

    // --- layer 4 ---
    mfma_gemm<64, 32, _Float16><<<GG, 256, 0, stream>>>(hsB, w4h, w4l, dinv, hsA, N);
    agg_kernel<32, false, float><<<CDIV(N, 64), 256, 0, stream>>>(hsA, rp, col, dinv, b4, out, N);
}

// Round 17
// 360.350 us; speedup vs baseline: 2.2500x; 1.0099x over previous
//
#include <hip/hip_runtime.h>

#define CDIV(a,b) (((a)+(b)-1)/(b))
#define BUK_SHIFT 10
#define EPB 4096   // edges per bucketize block

typedef float f32x4 __attribute__((ext_vector_type(4)));
typedef short short8 __attribute__((ext_vector_type(8)));
typedef _Float16 h16x8 __attribute__((ext_vector_type(8)));

// ---------------- bf16 helpers (RNE) ----------------

__device__ inline unsigned short rne_bf16(float f) {
    unsigned int u = __builtin_bit_cast(unsigned int, f);
    u += 0x7FFFu + ((u >> 16) & 1u);
    return (unsigned short)(u >> 16);
}

struct BF16Pair { short hi, lo; };

__device__ inline BF16Pair split_bf16(float f) {
    unsigned short h = rne_bf16(f);
    float fh = __builtin_bit_cast(float, (unsigned int)h << 16);
    BF16Pair p;
    p.hi = (short)h;
    p.lo = (short)rne_bf16(f - fh);
    return p;
}

// ---------------- bucketed edge sort (u32 records: (dst&1023)<<22 | src) ----------------

__global__ __launch_bounds__(256) void bkt_hist_kernel(const int* __restrict__ dst,
                                                       int* __restrict__ hcnt,
                                                       int E, int nbuk, int nblk) {
    __shared__ int lh[128];
    int t = threadIdx.x;
    for (int i = t; i < nbuk; i += 256) lh[i] = 0;
    __syncthreads();
    int base = blockIdx.x * EPB;
    int end = min(base + EPB, E);
    for (int e = base + t; e < end; e += 256)
        atomicAdd(&lh[dst[e] >> BUK_SHIFT], 1);
    __syncthreads();
    for (int i = t; i < nbuk; i += 256) hcnt[i * nblk + blockIdx.x] = lh[i];
}

__global__ __launch_bounds__(1024) void scan_flat_kernel(int* a, int n) {
    __shared__ int s[1024];
    int t = threadIdx.x;
    int per = (n + 1023) / 1024;
    int start = t * per, end = min(start + per, n);
    int sum = 0;
    for (int i = start; i < end; ++i) sum += a[i];
    s[t] = sum;
    __syncthreads();
    for (int off = 1; off < 1024; off <<= 1) {
        int x = (t >= off) ? s[t - off] : 0;
        __syncthreads();
        s[t] += x;
        __syncthreads();
    }
    int run = s[t] - sum;
    for (int i = start; i < end; ++i) { int v = a[i]; a[i] = run; run += v; }
}

__global__ __launch_bounds__(256) void bkt_scatter_kernel(const int* __restrict__ src,
                                                          const int* __restrict__ dst,
                                                          const int* __restrict__ obk,
                                                          unsigned int* __restrict__ ebuf,
                                                          int E, int nbuk, int nblk) {
    __shared__ int cur[128];
    int t = threadIdx.x;
    for (int i = t; i < nbuk; i += 256) cur[i] = obk[i * nblk + blockIdx.x];
    __syncthreads();
    int base = blockIdx.x * EPB;
    int end = min(base + EPB, E);
    for (int e = base + t; e < end; e += 256) {
        int d = dst[e], s = src[e];
        int b = d >> BUK_SHIFT;
        int pos = atomicAdd(&cur[b], 1);
        ebuf[pos] = ((unsigned)(d & 1023) << 22) | (unsigned)s;   // src < 2^22
    }
}

// ---------------- fused per-bucket CSR build (hist+scan+rp+dinv+fill) ----------------

__global__ __launch_bounds__(1024) void bucket_csr_kernel(const unsigned int* __restrict__ ebuf,
                                                          const int* __restrict__ hcnt,
                                                          int* __restrict__ rp,
                                                          float* __restrict__ dinv,
                                                          int* __restrict__ col,
                                                          int E, int N, int nbuk, int nblk) {
    __shared__ int lh[1024];
    __shared__ int lsc[1024];
    const int b = blockIdx.x;
    const int t = threadIdx.x;
    lh[t] = 0;
    __syncthreads();
    const int st = hcnt[b * nblk];
    const int en = (b + 1 < nbuk) ? hcnt[(b + 1) * nblk] : E;
    for (int e = st + t; e < en; e += 1024)
        atomicAdd(&lh[ebuf[e] >> 22], 1);
    __syncthreads();
    const int deg = lh[t];
    lsc[t] = deg;
    __syncthreads();
    for (int off = 1; off < 1024; off <<= 1) {
        int x = (t >= off) ? lsc[t - off] : 0;
        __syncthreads();
        lsc[t] += x;
        __syncthreads();
    }
    const int excl = lsc[t] - deg;
    const int node = (b << BUK_SHIFT) + t;
    if (node < N) {
        rp[node] = st + excl;
        dinv[node] = rsqrtf((float)deg + 1.0f);
    }
    if (b == 0 && t == 0) rp[N] = E;
    __syncthreads();
    lh[t] = st + excl;
    __syncthreads();
    for (int e = st + t; e < en; e += 1024) {
        unsigned int r = ebuf[e];
        int pos = atomicAdd(&lh[r >> 22], 1);
        col[pos] = (int)(r & 0x3FFFFFu);
    }
}

// ---------------- W prep: fp32 [K][F] -> split-bf16 in MFMA B-fragment order ----

template<int K, int F>
__global__ void wprep_kernel(const float* __restrict__ W, short* __restrict__ whi,
                             short* __restrict__ wlo) {
    constexpr int CB = F / 16;
    int idx = blockIdx.x * 256 + threadIdx.x;
    if (idx >= K * F) return;
    int e = idx & 7;
    int lane = (idx >> 3) & 63;
    int fc = idx >> 9;               // kb*CB + cb
    int kb = fc / CB, cb = fc % CB;
    int k = kb * 32 + (lane >> 4) * 8 + e;
    int colv = cb * 16 + (lane & 15);
    BF16Pair p = split_bf16(W[k * F + colv]);
    whi[idx] = p.hi;
    wlo[idx] = p.lo;
}

// ---------------- MFMA GEMM: H[N,F] = fp16( dinv[r] * (A[N,K] @ W[K,F]) ) --------
// B staged via global_load_lds (width=16) into a double buffer; counted vmcnt
// keeps next-tile loads in flight across raw s_barriers (never drains to 0 in
// the loop). A rows prefetched into registers with clamped row index so every
// wave issues exactly ALOADS loads (vmcnt count is exact for all waves).

template<int K, int F, typename AT>
__global__ __launch_bounds__(256) void mfma_gemm(const AT* __restrict__ A,
                                                 const short* __restrict__ Whi,
                                                 const short* __restrict__ Wlo,
                                                 const float* __restrict__ dinv,
                                                 _Float16* __restrict__ H, int N) {
    constexpr int CB = F / 16;
    constexpr int KB = K / 32;
    constexpr int HCH = CB * 64;          // 16B chunks per hi (or lo) stream per kb
    constexpr int CHUNKS = HCH * 2;       // exact multiple of 256 for F in {32,64,128}
    constexpr int CPT = CHUNKS / 256;     // 4 / 2 / 1
    constexpr int ALOADS = (sizeof(AT) == 4) ? 2 : 1;
    constexpr int VWAIT = CPT + ALOADS;   // 6 / 5 / 3 / 2

    __shared__ __align__(16) short Bs[2][CB * 1024];   // [buf][hi: CB*512 | lo: CB*512]

    const int tid = threadIdx.x;
    const int wid = tid >> 6, lane = tid & 63;
    const int rowf = lane & 15;
    const int kgrp = lane >> 4;
    const long long row0 = (long long)blockIdx.x * 64 + wid * 16;
    long long rA = row0 + rowf;
    if (rA >= N) rA = N - 1;              // clamp: always load (OOB rows never stored)

    f32x4 acc[CB] = {};
    float fvaC[8], fvaN[8];

    auto stage = [&](int b, int kb) {
#pragma unroll
        for (int i = 0; i < CPT; ++i) {
            int c = tid + i * 256;
            const short* g = (c < HCH) ? (Whi + (size_t)kb * (CB * 512) + (size_t)c * 8)
                                       : (Wlo + (size_t)kb * (CB * 512) + (size_t)(c - HCH) * 8);
            __builtin_amdgcn_global_load_lds(
                (const __attribute__((address_space(1))) unsigned int*)g,
                (__attribute__((address_space(3))) unsigned int*)(&Bs[b][(size_t)c * 8]),
                16, 0, 0);
        }
    };
    auto a_load = [&](float (&dst)[8], int kb) {
        const AT* ap = A + (size_t)rA * K + kb * 32 + kgrp * 8;
        if constexpr (sizeof(AT) == 4) {
            float4 f0 = ((const float4*)ap)[0];
            float4 f1 = ((const float4*)ap)[1];
            dst[0] = f0.x; dst[1] = f0.y; dst[2] = f0.z; dst[3] = f0.w;
            dst[4] = f1.x; dst[5] = f1.y; dst[6] = f1.z; dst[7] = f1.w;
        } else {
            h16x8 hv = *(const h16x8*)ap;
#pragma unroll
            for (int j = 0; j < 8; ++j) dst[j] = (float)hv[j];
        }
    };

    stage(0, 0);
    a_load(fvaC, 0);

    for (int kb = 0; kb < KB; ++kb) {
        const int b = kb & 1;
        if (kb + 1 < KB) {
            stage(b ^ 1, kb + 1);         // next B tile flies across the barrier
            a_load(fvaN, kb + 1);         // next A fragment (register prefetch)
        }
        __builtin_amdgcn_sched_barrier(0);
        if (kb + 1 < KB) {
            // wait for buf b + fvaC (older); allow the VWAIT newest to stay in flight
            if constexpr (VWAIT == 6)      asm volatile("s_waitcnt vmcnt(6)" ::: "memory");
            else if constexpr (VWAIT == 5) asm volatile("s_waitcnt vmcnt(5)" ::: "memory");
            else if constexpr (VWAIT == 3) asm volatile("s_waitcnt vmcnt(3)" ::: "memory");
            else                           asm volatile("s_waitcnt vmcnt(2)" ::: "memory");
        } else {
            asm volatile("s_waitcnt vmcnt(0)" ::: "memory");
        }
        __builtin_amdgcn_s_barrier();
        __builtin_amdgcn_sched_barrier(0);

        short8 ahi, alo;
#pragma unroll
        for (int j = 0; j < 8; ++j) {
            BF16Pair p = split_bf16(fvaC[j]);
            ahi[j] = p.hi;
            alo[j] = p.lo;
        }
#pragma unroll
        for (int cb = 0; cb < CB; ++cb) {
            short8 bhi = *(const short8*)&Bs[b][((size_t)cb * 64 + lane) * 8];
            short8 blo = *(const short8*)&Bs[b][CB * 512 + ((size_t)cb * 64 + lane) * 8];
            acc[cb] = __builtin_amdgcn_mfma_f32_16x16x32_bf16(ahi, bhi, acc[cb], 0, 0, 0);
            acc[cb] = __builtin_amdgcn_mfma_f32_16x16x32_bf16(alo, bhi, acc[cb], 0, 0, 0);
            acc[cb] = __builtin_amdgcn_mfma_f32_16x16x32_bf16(ahi, blo, acc[cb], 0, 0, 0);
        }
        if (kb + 1 < KB) {
#pragma unroll
            for (int j = 0; j < 8; ++j) fvaC[j] = fvaN[j];
        }
        __builtin_amdgcn_s_barrier();     // all reads of buf b done before it is re-staged
        __builtin_amdgcn_sched_barrier(0);
    }

    // D layout: col = lane&15, row = (lane>>4)*4 + j ; scale by dinv[row], cvt fp16
    const int rsub = (lane >> 4) * 4;
    long long rbase = row0 + rsub;
    float dv[4];
#pragma unroll
    for (int j = 0; j < 4; ++j) dv[j] = (rbase + j < N) ? dinv[rbase + j] : 0.f;
#pragma unroll
    for (int cb = 0; cb < CB; ++cb) {
        int colv = cb * 16 + rowf;
#pragma unroll
        for (int j = 0; j < 4; ++j) {
            long long r = rbase + j;
            if (r < N) H[(size_t)r * F + colv] = (_Float16)(acc[cb][j] * dv[j]);
        }
    }
}

// ---------------- fused CSR aggregation (fp16 gather, fp32 accum) ----------------

template<int F, bool RELU, typename OutT>
__global__ __launch_bounds__(256) void agg_kernel(const _Float16* __restrict__ hs,
                                                  const int* __restrict__ rp,
                                                  const int* __restrict__ col,
                                                  const float* __restrict__ dinv,
                                                  const float* __restrict__ bias,
                                                  OutT* __restrict__ out, int N) {
    constexpr int LPN = F / 8;            // lanes per node, 16B/lane
    constexpr int NPB = 256 / LPN;
    const int tid = threadIdx.x;
    const int lane = tid % LPN;
    const int node = blockIdx.x * NPB + tid / LPN;
    if (node >= N) return;

    const int f0 = lane * 8;
    const _Float16* hbase = hs + f0;

    float acc[8];
    {
        h16x8 sv = *(const h16x8*)(hbase + (size_t)node * F);
#pragma unroll
        for (int v = 0; v < 8; ++v) acc[v] = (float)sv[v];
    }

    int e = rp[node];
    const int e1 = rp[node + 1];
    for (; e + 4 <= e1; e += 4) {
        int s0 = col[e], s1 = col[e + 1], s2 = col[e + 2], s3 = col[e + 3];
        h16x8 v0 = *(const h16x8*)(hbase + (size_t)s0 * F);
        h16x8 v1 = *(const h16x8*)(hbase + (size_t)s1 * F);
        h16x8 v2 = *(const h16x8*)(hbase + (size_t)s2 * F);
        h16x8 v3 = *(const h16x8*)(hbase + (size_t)s3 * F);
#pragma unroll
        for (int v = 0; v < 8; ++v)
            acc[v] += ((float)v0[v] + (float)v1[v]) + ((float)v2[v] + (float)v3[v]);
    }
    for (; e < e1; ++e) {
        h16x8 v0 = *(const h16x8*)(hbase + (size_t)col[e] * F);
#pragma unroll
        for (int v = 0; v < 8; ++v) acc[v] += (float)v0[v];
    }

    const float self = dinv[node];
    OutT* op = out + (size_t)node * F + f0;
    const float* bp = bias + f0;
#pragma unroll
    for (int v = 0; v < 8; ++v) {
        float r = fmaf(acc[v], self, bp[v]);
        if (RELU) r = fmaxf(r, 0.f);
        op[v] = (OutT)r;
    }
}

// ---------------- launcher ----------------

extern "C" void kernel_launch(void* const* d_in, const int* in_sizes, int n_in,
                              void* d_out, int out_size, void* d_ws, size_t ws_size,
                              hipStream_t stream) {
    const float* x  = (const float*)d_in[0];
    const int*   ei = (const int*)d_in[1];
    const float* W1 = (const float*)d_in[2];
    const float* b1 = (const float*)d_in[3];
    const float* W2 = (const float*)d_in[4];
    const float* b2 = (const float*)d_in[5];
    const float* W3 = (const float*)d_in[6];
    const float* b3 = (const float*)d_in[7];
    const float* W4 = (const float*)d_in[8];
    const float* b4 = (const float*)d_in[9];

    const int N = in_sizes[0] / 256;
    const int E = in_sizes[1] / 2;
    const int* src = ei;
    const int* dst = ei + E;

    const int nbuk = ((N - 1) >> BUK_SHIFT) + 1;
    const int nblk = CDIV(E, EPB);

    char* base = (char*)d_ws;
    size_t o = 0;
    auto alloc = [&](size_t bytes) { char* p = base + o; o += (bytes + 255) & ~(size_t)255; return p; };
    int*   rp   = (int*)  alloc(sizeof(int) * (N + 1));
    float* dinv = (float*)alloc(sizeof(float) * N);
    int*   col  = (int*)  alloc(sizeof(int) * E);
    int*   hcnt = (int*)  alloc(sizeof(int) * (size_t)nbuk * nblk);
    unsigned int* ebuf = (unsigned int*)alloc(sizeof(unsigned int) * E);
    short* w1h  = (short*)alloc(sizeof(short) * 256 * 128);
    short* w1l  = (short*)alloc(sizeof(short) * 256 * 128);
    short* w2h  = (short*)alloc(sizeof(short) * 128 * 128);
    short* w2l  = (short*)alloc(sizeof(short) * 128 * 128);
    short* w3h  = (short*)alloc(sizeof(short) * 128 * 64);
    short* w3l  = (short*)alloc(sizeof(short) * 128 * 64);
    short* w4h  = (short*)alloc(sizeof(short) * 64 * 32);
    short* w4l  = (short*)alloc(sizeof(short) * 64 * 32);
    _Float16* hsA = (_Float16*)alloc(sizeof(_Float16) * (size_t)N * 128);  // ping
    _Float16* hsB = (_Float16*)alloc(sizeof(_Float16) * (size_t)N * 128);  // pong
    float* out  = (float*)d_out;

    // --- weight prep (split-bf16, fragment-swizzled) ---
    wprep_kernel<256, 128><<<CDIV(256 * 128, 256), 256, 0, stream>>>(W1, w1h, w1l);
    wprep_kernel<128, 128><<<CDIV(128 * 128, 256), 256, 0, stream>>>(W2, w2h, w2l);
    wprep_kernel<128, 64><<<CDIV(128 * 64, 256), 256, 0, stream>>>(W3, w3h, w3l);
    wprep_kernel<64, 32><<<CDIV(64 * 32, 256), 256, 0, stream>>>(W4, w4h, w4l);

    // --- bucketed edge sort + fused CSR build ---
    bkt_hist_kernel<<<nblk, 256, 0, stream>>>(dst, hcnt, E, nbuk, nblk);
    scan_flat_kernel<<<1, 1024, 0, stream>>>(hcnt, nbuk * nblk);
    bkt_scatter_kernel<<<nblk, 256, 0, stream>>>(src, dst, hcnt, ebuf, E, nbuk, nblk);
    bucket_csr_kernel<<<nbuk, 1024, 0, stream>>>(ebuf, hcnt, rp, dinv, col, E, N, nbuk, nblk);

    const int GG = CDIV(N, 64);

    // --- layer 1 ---
    mfma_gemm<256, 128, float><<<GG, 256, 0, stream>>>(x, w1h, w1l, dinv, hsA, N);
    agg_kernel<128, true, _Float16><<<CDIV(N, 16), 256, 0, stream>>>(hsA, rp, col, dinv, b1, hsB, N);

    // --- layer 2 ---
    mfma_gemm<128, 128, _Float16><<<GG, 256, 0, stream>>>(hsB, w2h, w2l, dinv, hsA, N);
    agg_kernel<128, true, _Float16><<<CDIV(N, 16), 256, 0, stream>>>(hsA, rp, col, dinv, b2, hsB, N);

    // --- layer 3 ---
    mfma_gemm<128, 64, _Float16><<<GG, 256, 0, stream>>>(hsB, w3h, w3l, dinv, hsA, N);
    agg_kernel<64, true, _Float16><<<CDIV(N, 32), 256, 0, stream>>>(hsA, rp, col, dinv, b3, hsB, N);

    // --- layer 4 ---
    mfma_gemm<64, 32, _Float16><<<GG, 256, 0, stream>>>(hsB, w4h, w4l, dinv, hsA, N);
    agg_kernel<32, false, float><<<CDIV(N, 64), 256, 0, stream>>>(hsA, rp, col, dinv, b4, out, N);
}